// Round 2
// baseline (620.093 us; speedup 1.0000x reference)
//
#include <hip/hip_runtime.h>
#include <cstdint>
#include <cstddef>

typedef _Float16 h16;
typedef __attribute__((ext_vector_type(8))) _Float16 h16x8;
typedef __attribute__((ext_vector_type(4))) _Float16 h16x4;
typedef __attribute__((ext_vector_type(4))) float f32x4;

constexpr int B_ = 64, LD = 512, LQ = 128, DIM = 512, STEPS = 2;
constexpr int MD = B_ * LD;   // 32768 d-rows total
constexpr int MQ = B_ * LQ;   // 8192 q-rows total
constexpr int KST = LD + LQ;  // 640 stacked-neighbor K
constexpr int KAGG = KST + DIM;  // 1152 = mask|node augmented K for agg GEMM

// async global->LDS, 16B per lane; LDS dest must be wave-uniform base + lane*16
#define ASYNC16(gp, lp)                                                          \
  __builtin_amdgcn_global_load_lds(                                              \
      (const __attribute__((address_space(1))) unsigned int*)(gp),               \
      (__attribute__((address_space(3))) unsigned int*)(lp), 16, 0, 0)

// A GEMM operand that switches source at k = ksplit (both K-contiguous).
struct Src {
  const h16* p0; int s0; long bstr0;  // rows for k in [0, ksplit)
  const h16* p1; int s1; long bstr1;  // rows for k in [ksplit, K)
  int ksplit;
};

// ---------------------------------------------------------------------------
// C = A * B^T tile kernel body. Block tile BM x 256, 512 threads = 8 waves.
// BM=256: waves as 2x4 (wave tile 128x64); BM=128: 1x4. Each wave: 8x4
// mfma_f32_16x16x32_f16 frags (fp32 accum).
// RATIONALE (r1 post-mortem): both GEMMs are staged-bytes-bound (~6.4 TB/s
// through the DMA/L2-miss path; schedule changes were perf-neutral). 256-wide
// N halves panel re-reads: staged bytes/MFMA 192B -> 128B.
// Pipeline: 3 LDS buffers, prefetch depth 2, counted s_waitcnt vmcnt(L)
// + raw s_barrier per K-step; L = DMA insts/tile/wave (4 for BM=256, 3 for
// BM=128) so the younger in-flight tile is never drained.
// LDS swizzle (DMA-compatible, lane-linear dest): 16B chunk (row,kq) at
// panel chunk index row*4 + (kq ^ e(row)), e(row)=(row^(row>>2))&3.
// Staging thread t (0..511) covers panel chunk t (+512 for the second
// 128-row half); fragment ds_read_b128 conflict-free as before.
// MFMA 16x16x32 layouts (measured, m89/m91):
//   A-frag: m = lane&15, k = quad*8 + j ; B-frag: n = lane&15, k = quad*8+j
//   C/D:    col(n) = lane&15, row(m) = quad*4 + r
// ---------------------------------------------------------------------------
template <int BM, class Epi>
__device__ __forceinline__ void gemm_body(int b, long tileM, long tileN,
                                          Src sa, Src sb, int K,
                                          const Epi& epi, h16* lds) {
  constexpr int AE = BM * 32;          // A elems per buffer
  constexpr int BUFE = AE + 256 * 32;  // buffer stride in h16 elems
  constexpr int NA = BM / 128;         // A chunks per thread: 2 or 1

  const int tid = threadIdx.x;         // 0..511
  const int lane = tid & 63;
  const int wv = tid >> 6;             // 0..7
  const int wr = (BM == 256) ? (wv >> 2) : 0;
  const int wc = wv & 3;
  const int quad = lane >> 4, l16 = lane & 15;

  // staging mapping: thread t -> chunk u of segment sb (and sb+2)
  const int u = tid & 255;
  const int sb2 = tid >> 8;                     // 0..1
  const int r = u >> 2;                         // row within 64-row segment
  const int es = (r ^ (r >> 2)) & 3;
  const int kq = (u & 3) ^ es;                  // permuted k-quarter

  const h16* pa[2][NA];
  const h16* pb[2][2];
#pragma unroll
  for (int s = 0; s < NA; s++) {
    const long row = tileM + sb2 * 64 + r + 128 * s;
    pa[0][s] = sa.p0 + (size_t)b * sa.bstr0 + row * (long)sa.s0 + kq * 8;
    pa[1][s] = sa.p1 + (size_t)b * sa.bstr1 + row * (long)sa.s1 + kq * 8 - sa.ksplit;
  }
#pragma unroll
  for (int s = 0; s < 2; s++) {
    const long row = tileN + sb2 * 64 + r + 128 * s;
    pb[0][s] = sb.p0 + (size_t)b * sb.bstr0 + row * (long)sb.s0 + kq * 8;
    pb[1][s] = sb.p1 + (size_t)b * sb.bstr1 + row * (long)sb.s1 + kq * 8 - sb.ksplit;
  }

  // fragment LDS element offsets (buf 0); e depends only on l16
  const int ef = (l16 ^ (l16 >> 2)) & 3;
  int offA[8], offB[4];
#pragma unroll
  for (int i = 0; i < 8; i++) {
    const int row = wr * 128 + i * 16 + l16;
    offA[i] = (row * 4 + (quad ^ ef)) * 8;
  }
#pragma unroll
  for (int j = 0; j < 4; j++) {
    const int row = wc * 64 + j * 16 + l16;
    offB[j] = AE + (row * 4 + (quad ^ ef)) * 8;
  }

  f32x4 acc[8][4] = {};
  const int T = K >> 5;

  auto dmaTile = [&](int t, int off) {
    const int k0 = t * 32;
    h16* base = lds + off + tid * 8;
    const int sel = (k0 >= sa.ksplit);
#pragma unroll
    for (int s = 0; s < NA; s++) ASYNC16(pa[sel][s] + k0, base + 4096 * s);
    const int selb = (k0 >= sb.ksplit);
#pragma unroll
    for (int s = 0; s < 2; s++) ASYNC16(pb[selb][s] + k0, base + AE + 4096 * s);
  };
  auto mfmaStep = [&](int off) {
    h16x8 af[8], bf[4];
#pragma unroll
    for (int i = 0; i < 8; i++) af[i] = *(const h16x8*)(lds + off + offA[i]);
#pragma unroll
    for (int j = 0; j < 4; j++) bf[j] = *(const h16x8*)(lds + off + offB[j]);
#pragma unroll
    for (int i = 0; i < 8; i++)
#pragma unroll
      for (int j = 0; j < 4; j++)
        acc[i][j] = __builtin_amdgcn_mfma_f32_16x16x32_f16(af[i], bf[j], acc[i][j], 0, 0, 0);
  };

  // prologue: 2 tiles in flight
  dmaTile(0, 0);
  dmaTile(1, BUFE);

  int co = 0;            // buffer offset to consume (tile t)
  int no = 2 * BUFE;     // buffer offset for issue (tile t+2)
  for (int t = 0; t < T - 1; ++t) {
    // own dma(t) done; dma(t+1) stays in flight (counted wait, no drain)
    if constexpr (NA == 2) asm volatile("s_waitcnt vmcnt(4)" ::: "memory");
    else                   asm volatile("s_waitcnt vmcnt(3)" ::: "memory");
    __builtin_amdgcn_s_barrier();            // all waves' dma(t) done; WAR gate
    asm volatile("" ::: "memory");
    __builtin_amdgcn_sched_barrier(0);
    if (t + 2 < T) dmaTile(t + 2, no);
    mfmaStep(co);
    co = (co == 2 * BUFE) ? 0 : co + BUFE;
    no = (no == 2 * BUFE) ? 0 : no + BUFE;
  }
  // last K-step: nothing younger in flight -> full drain
  asm volatile("s_waitcnt vmcnt(0)" ::: "memory");
  __builtin_amdgcn_s_barrier();
  asm volatile("" ::: "memory");
  __builtin_amdgcn_sched_barrier(0);
  mfmaStep(co);

#pragma unroll
  for (int i = 0; i < 8; i++) {
#pragma unroll
    for (int j = 0; j < 4; j++) {
      const int gm0 = (int)tileM + wr * 128 + i * 16 + quad * 4;
      const int gn  = (int)tileN + wc * 64 + j * 16 + l16;
#pragma unroll
      for (int rr = 0; rr < 4; rr++) epi(b, gm0 + rr, gn, acc[i][j][rr]);
    }
  }
}

// --- epilogues --------------------------------------------------------------
// Dense GEMM: A = [W_x|W_y] (1024 rows), Bt = node (all batches), C[o][node].
struct EpiDense {
  const float* w;   // gate per node (indexed by gn)
  h16* stackA;      // gm <  512 -> stackA[b][gm][offA + l]
  h16* stackB;      // gm >= 512 -> stackB[b][gm-512][offB + l]
  int lnShift;      // nodes-per-batch shift: 9 (d) or 7 (q)
  int offA, offB;
  __device__ void operator()(int, int gm, int gn, float v) const {
    const int b = gn >> lnShift, l = gn & ((1 << lnShift) - 1);
    const h16 sv = (h16)(w[gn] * v);
    if (gm < 512)
      stackA[((size_t)b * 512 + gm) * 640 + offA + l] = sv;
    else
      stackB[((size_t)b * 512 + (gm - 512)) * 640 + offB + l] = sv;
  }
};
// Agg GEMM: A = [mask'|node], Bt = [stackT|W_self], C[i][c] = self + msg/nb.
// nodeNext == nullptr on the last iteration (result never re-read).
struct EpiAgg {
  const float* bias;  // b_self[c]
  float* out;         // fp32 final output or nullptr
  h16* nodeNext;      // next-iteration node buffer [i][c], or nullptr
  int rowsPerB;       // 512 (d) or 128 (q)
  __device__ void operator()(int b, int gm, int gn, float v) const {
    const size_t row = (size_t)b * rowsPerB + gm;
    const float val = fmaxf(v + bias[gn], 0.f);
    if (out) out[row * 512 + gn] = val;
    if (nodeNext) nodeNext[row * 512 + gn] = (h16)val;
  }
};

// ---------------------------------------------------------------------------
// Combined dense launch: 640 blocks of 512 thr. g = x*160 + yy; x = M-tile of
// 256 (0..3), yy<128 -> d-job (tileN=yy*256), else q-job (yy-128). Same-yy
// blocks are 160 apart => same XCD (L2 reuse of the shared node B-panel).
// ---------------------------------------------------------------------------
__global__ __launch_bounds__(512, 2) void k_dense(Src saD, Src sbD, EpiDense epiD,
                                                  Src saQ, Src sbQ, EpiDense epiQ) {
  __shared__ __align__(16) h16 lds[3 * (256 * 32 + 256 * 32)];  // 96 KB, 3 bufs
  const int g = blockIdx.x;
  const int x = g / 160;
  const int yy = g % 160;
  if (yy < 128)
    gemm_body<256>(0, (long)x * 256, (long)yy * 256, saD, sbD, 512, epiD, lds);
  else
    gemm_body<256>(0, (long)x * 256, (long)(yy - 128) * 256, saQ, sbQ, 512, epiQ, lds);
}

// Combined agg launch: 384 blocks of 512 thr. g = inner*64 + b. q-jobs (2 per
// batch, BM=128) dispatch FIRST so they pair with d-blocks instead of forming
// a tail. inner<2 -> q (tileN=inner*256); else i2=inner-2 -> d (x=i2>>1,
// y=i2&1). Same-batch blocks are 64 apart => same XCD.
__global__ __launch_bounds__(512, 2) void k_agg(Src saD, Src sbD, EpiAgg epiD,
                                                Src saQ, Src sbQ, EpiAgg epiQ) {
  __shared__ __align__(16) h16 lds[3 * (256 * 32 + 256 * 32)];  // 96 KB, 3 bufs
  const int g = blockIdx.x;
  const int b = g & 63;
  const int inner = g >> 6;
  if (inner >= 2) {
    const int i2 = inner - 2;
    gemm_body<256>(b, (long)(i2 >> 1) * 256, (long)(i2 & 1) * 256, saD, sbD, KAGG, epiD, lds);
  } else {
    gemm_body<128>(b, 0L, (long)inner * 256, saQ, sbQ, KAGG, epiQ, lds);
  }
}

// --- small kernels ----------------------------------------------------------
__global__ __launch_bounds__(256) void k_convert(const float* __restrict__ dn,
                                                 const float* __restrict__ qn,
                                                 h16* __restrict__ dnb,
                                                 h16* __restrict__ qnb) {
  const size_t i4 = ((size_t)blockIdx.x * 256 + threadIdx.x) * 4;
  constexpr size_t TD = (size_t)MD * DIM;
  const float* src; h16* dst; size_t idx;
  if (i4 < TD) { src = dn; dst = dnb; idx = i4; }
  else         { src = qn; dst = qnb; idx = i4 - TD; }
  const float4 v = *(const float4*)&src[idx];
  h16x4 o; o.x = (h16)v.x; o.y = (h16)v.y; o.z = (h16)v.z; o.w = (h16)v.w;
  *(h16x4*)&dst[idx] = o;
}

__global__ __launch_bounds__(256) void k_wcat(const float* __restrict__ Wself,
                                              const float* __restrict__ Wdd,
                                              const float* __restrict__ Wqd,
                                              const float* __restrict__ Wqq,
                                              const float* __restrict__ Wdq,
                                              h16* __restrict__ catD,
                                              h16* __restrict__ catQ) {
  const int i = blockIdx.x * 256 + threadIdx.x;  // < 1536*512
  float vD, vQ;
  if (i < 512 * 512)       { vD = Wself[i];            vQ = vD; }
  else if (i < 1024 * 512) { vD = Wdd[i - 512 * 512];  vQ = Wqq[i - 512 * 512]; }
  else                     { vD = Wqd[i - 1024 * 512]; vQ = Wdq[i - 1024 * 512]; }
  catD[i] = (h16)vD; catQ[i] = (h16)vQ;
}

// maskD'[b][i][j] = graph/nb : j<512 dd, else dq (premultiplied by 1/max(nb,1))
__global__ __launch_bounds__(256) void k_maskD(const int* __restrict__ dd,
                                               const int* __restrict__ dq,
                                               h16* __restrict__ maskD) {
  const int row = blockIdx.x * 4 + (threadIdx.x >> 6);
  const int lane = threadIdx.x & 63;
  const int* pdd = dd + (size_t)row * 512;
  const int* pdq = dq + (size_t)row * 128;
  h16* pm = maskD + (size_t)row * 640;
  float vals[10];
  float s = 0.f;
#pragma unroll
  for (int t = 0; t < 10; t++) {
    const int j = lane + t * 64;
    const float v = (float)((j < 512) ? pdd[j] : pdq[j - 512]);
    vals[t] = v; s += v;
  }
  for (int m = 32; m; m >>= 1) s += __shfl_xor(s, m);
  const float inv = 1.f / fmaxf(s, 1.f);
#pragma unroll
  for (int t = 0; t < 10; t++) pm[lane + t * 64] = (h16)(vals[t] * inv);
}

__global__ __launch_bounds__(256) void k_maskQ(const int* __restrict__ qq,
                                               const int* __restrict__ qd,
                                               h16* __restrict__ maskQ) {
  const int row = blockIdx.x * 4 + (threadIdx.x >> 6);
  const int lane = threadIdx.x & 63;
  const int* pqq = qq + (size_t)row * 128;
  const int* pqd = qd + (size_t)row * 512;
  h16* pm = maskQ + (size_t)row * 640;
  float vals[10];
  float s = 0.f;
#pragma unroll
  for (int t = 0; t < 10; t++) {
    const int j = lane + t * 64;
    const float v = (float)((j < 128) ? pqq[j] : pqd[j - 128]);
    vals[t] = v; s += v;
  }
  for (int m = 32; m; m >>= 1) s += __shfl_xor(s, m);
  const float inv = 1.f / fmaxf(s, 1.f);
#pragma unroll
  for (int t = 0; t < 10; t++) pm[lane + t * 64] = (h16)(vals[t] * inv);
}

// sigmoid gate per node row: one wave per row (d rows then q rows)
__global__ __launch_bounds__(256) void k_w(const h16* __restrict__ dnb,
                                           const h16* __restrict__ qnb,
                                           const float* __restrict__ Wnw,
                                           const float* __restrict__ bnw,
                                           float* __restrict__ d_w,
                                           float* __restrict__ q_w,
                                           float* __restrict__ adw,
                                           float* __restrict__ aqw, int it) {
  const int row = blockIdx.x * 4 + (threadIdx.x >> 6);
  const int lane = threadIdx.x & 63;
  const bool isD = row < MD;
  const h16* node = isD ? dnb + (size_t)row * 512 : qnb + (size_t)(row - MD) * 512;
  const h16x8 v = *(const h16x8*)&node[lane * 8];
  const float4 w0 = *(const float4*)&Wnw[lane * 8];
  const float4 w1 = *(const float4*)&Wnw[lane * 8 + 4];
  float s = (float)v[0] * w0.x + (float)v[1] * w0.y + (float)v[2] * w0.z +
            (float)v[3] * w0.w + (float)v[4] * w1.x + (float)v[5] * w1.y +
            (float)v[6] * w1.z + (float)v[7] * w1.w;
  for (int m = 32; m; m >>= 1) s += __shfl_xor(s, m);
  if (lane == 0) {
    const float w = 1.f / (1.f + expf(-(s + bnw[0])));
    if (isD) {
      d_w[row] = w;
      adw[((size_t)(row >> 9) * STEPS + it) * 512 + (row & 511)] = w;
    } else {
      const int rq = row - MD;
      q_w[rq] = w;
      aqw[((size_t)(rq >> 7) * STEPS + it) * 128 + (rq & 127)] = w;
    }
  }
}

// ---------------------------------------------------------------------------
extern "C" void kernel_launch(void* const* d_in, const int* in_sizes, int n_in,
                              void* d_out, int out_size, void* d_ws, size_t ws_size,
                              hipStream_t stream) {
  (void)in_sizes; (void)n_in; (void)out_size; (void)ws_size;

  const float* d_node = (const float*)d_in[0];
  const float* q_node = (const float*)d_in[1];
  const int*   qq     = (const int*)d_in[2];
  const int*   dq     = (const int*)d_in[3];
  const int*   dd     = (const int*)d_in[4];
  const int*   qd     = (const int*)d_in[5];
  const float* W_nw   = (const float*)d_in[6];
  const float* b_nw   = (const float*)d_in[7];
  const float* W_self = (const float*)d_in[8];
  const float* b_self = (const float*)d_in[9];
  const float* W_dd   = (const float*)d_in[10];
  const float* W_qq   = (const float*)d_in[11];
  const float* W_dq   = (const float*)d_in[12];
  const float* W_qd   = (const float*)d_in[13];

  float* outd = (float*)d_out;                  // [B,Ld,D]
  float* outq = outd + (size_t)MD * DIM;        // [B,Lq,D]
  float* adw  = outq + (size_t)MQ * DIM;        // [B,STEPS,Ld]
  float* aqw  = adw + (size_t)B_ * STEPS * LD;  // [B,STEPS,Lq]

  char* p = (char*)d_ws;
  auto alloc = [&](size_t bytes) { char* r = p; p += (bytes + 255) & ~(size_t)255; return r; };
  h16* dnode[2], *qnode[2];
  dnode[0] = (h16*)alloc((size_t)MD * DIM * 2);
  dnode[1] = (h16*)alloc((size_t)MD * DIM * 2);
  qnode[0] = (h16*)alloc((size_t)MQ * DIM * 2);
  qnode[1] = (h16*)alloc((size_t)MQ * DIM * 2);
  h16* catD    = (h16*)alloc((size_t)1536 * 512 * 2);
  h16* catQ    = (h16*)alloc((size_t)1536 * 512 * 2);
  h16* maskD   = (h16*)alloc((size_t)B_ * LD * KST * 2);
  h16* maskQ   = (h16*)alloc((size_t)B_ * LQ * KST * 2);
  h16* stackDT = (h16*)alloc((size_t)B_ * 512 * KST * 2);
  h16* stackQT = (h16*)alloc((size_t)B_ * 512 * KST * 2);
  float* d_wb  = (float*)alloc((size_t)MD * 4);
  float* q_wb  = (float*)alloc((size_t)MQ * 4);

  // one-time prep
  k_convert<<<dim3((MD * DIM + MQ * DIM) / 4 / 256), 256, 0, stream>>>(d_node, q_node, dnode[0], qnode[0]);
  k_wcat<<<dim3(1536 * 512 / 256), 256, 0, stream>>>(W_self, W_dd, W_qd, W_qq, W_dq, catD, catQ);
  k_maskD<<<dim3(MD / 4), 256, 0, stream>>>(dd, dq, maskD);
  k_maskQ<<<dim3(MQ / 4), 256, 0, stream>>>(qq, qd, maskQ);

  for (int it = 0; it < STEPS; it++) {
    const bool last = (it == STEPS - 1);
    h16* ncur_d = dnode[it & 1];
    h16* nnext_d = dnode[(it & 1) ^ 1];
    h16* ncur_q = qnode[it & 1];
    h16* nnext_q = qnode[(it & 1) ^ 1];

    k_w<<<dim3((MD + MQ) / 4), 256, 0, stream>>>(ncur_d, ncur_q, W_nw, b_nw, d_wb, q_wb, adw, aqw, it);

    // combined dense: d-job A=catD[512:1536]=[W_dd|W_qd] Bt=dnode;
    //                 q-job A=catQ[512:1536]=[W_qq|W_dq] Bt=qnode
    {
      Src saD{catD + 512 * 512, 512, 0, catD + 512 * 512, 512, 0, 512};
      Src sbD{ncur_d, 512, 0, ncur_d, 512, 0, 512};
      Src saQ{catQ + 512 * 512, 512, 0, catQ + 512 * 512, 512, 0, 512};
      Src sbQ{ncur_q, 512, 0, ncur_q, 512, 0, 512};
      k_dense<<<dim3(640), 512, 0, stream>>>(
          saD, sbD, EpiDense{d_wb, stackDT, stackQT, 9, 0, 128},
          saQ, sbQ, EpiDense{q_wb, stackQT, stackDT, 7, 0, 512});
    }
    // combined agg: d-job A=[maskD'|dnode] Bt=[stackDT|W_self];
    //               q-job A=[maskQ'|qnode] Bt=[stackQT|W_self]
    {
      Src saD{maskD, 640, (long)LD * KST, ncur_d, 512, (long)LD * DIM, KST};
      Src sbD{stackDT, 640, (long)512 * KST, catD, 512, 0, KST};
      Src saQ{maskQ, 640, (long)LQ * KST, ncur_q, 512, (long)LQ * DIM, KST};
      Src sbQ{stackQT, 640, (long)512 * KST, catQ, 512, 0, KST};
      k_agg<<<dim3(384), 512, 0, stream>>>(
          saD, sbD, EpiAgg{b_self, last ? outd : nullptr, last ? nullptr : nnext_d, 512},
          saQ, sbQ, EpiAgg{b_self, last ? outq : nullptr, last ? nullptr : nnext_q, 128});
    }
  }
}

// Round 3
// 568.952 us; speedup vs baseline: 1.0899x; 1.0899x over previous
//
#include <hip/hip_runtime.h>
#include <cstdint>
#include <cstddef>

typedef _Float16 h16;
typedef __attribute__((ext_vector_type(8))) _Float16 h16x8;
typedef __attribute__((ext_vector_type(4))) _Float16 h16x4;
typedef __attribute__((ext_vector_type(4))) float f32x4;

constexpr int B_ = 64, LD = 512, LQ = 128, DIM = 512, STEPS = 2;
constexpr int MD = B_ * LD;   // 32768 d-rows total
constexpr int MQ = B_ * LQ;   // 8192 q-rows total
constexpr int KST = LD + LQ;  // 640 stacked-neighbor K
constexpr int KAGG = KST + DIM;  // 1152 = mask|node augmented K for agg GEMM

// async global->LDS, 16B per lane; LDS dest must be wave-uniform base + lane*16
#define ASYNC16(gp, lp)                                                          \
  __builtin_amdgcn_global_load_lds(                                              \
      (const __attribute__((address_space(1))) unsigned int*)(gp),               \
      (__attribute__((address_space(3))) unsigned int*)(lp), 16, 0, 0)

// A GEMM operand that switches source at k = ksplit (both K-contiguous).
struct Src {
  const h16* p0; int s0; long bstr0;  // rows for k in [0, ksplit)
  const h16* p1; int s1; long bstr1;  // rows for k in [ksplit, K)
  int ksplit;
};

// ---------------------------------------------------------------------------
// C = A * B^T tile body. 512 threads = 8 waves as 2x4; wave tile
// (WM*16) x (WN*16); block tile BM=WM*32 x BN=WN*64.
//   dense & agg-d: WM=8,WN=4 -> 256x256;  agg-q: WM=4,WN=2 -> 128x128.
// r2 post-mortem: at 1 blk/CU the coarse 2-barrier K-step left all stalls
// exposed (MfmaUtil 19%). This revision ports the 8-phase idea: each 32-wide
// K-step is split into two {DMA-issue || ds_read || setprio MFMA} phases
// separated by s_barrier, with counted vmcnt (never 0 in-loop) at K-step
// boundaries only. 3 LDS buffers, prefetch depth 2.
// LDS swizzle (DMA-compatible, lane-linear dest): 16B chunk (row,kq) at
// panel chunk index row*4 + (kq ^ e(row)), e(row)=(row^(row>>2))&3.
// Staging thread t covers panel chunk t (+512/half); fragment ds_read_b128
// conflict-free (verified r1/r2).
// MFMA 16x16x32 layouts (measured, m89/m91):
//   A-frag: m = lane&15, k = quad*8 + j ; B-frag: n = lane&15, k = quad*8+j
//   C/D:    col(n) = lane&15, row(m) = quad*4 + r
// ---------------------------------------------------------------------------
template <int WM, int WN, class Epi>
__device__ __forceinline__ void gemm_body(int b, long tileM, long tileN,
                                          Src sa, Src sb, int K,
                                          const Epi& epi, h16* lds) {
  constexpr int BM = WM * 32;
  constexpr int BN = WN * 64;
  constexpr int AE = BM * 32;          // A elems per buffer
  constexpr int BUFE = (BM + BN) * 32; // buffer stride in h16 elems
  constexpr int NA = BM / 128;         // A DMA insts per thread per K-step
  constexpr int NB = BN / 128;         // B DMA insts per thread per K-step
  constexpr int LT = NA + NB;          // loads per tile per thread
  constexpr int HM = WM / 2;

  const int tid = threadIdx.x;         // 0..511
  const int lane = tid & 63;
  const int wv = tid >> 6;             // 0..7
  const int wr = wv >> 2, wc = wv & 3; // 2x4 wave grid
  const int quad = lane >> 4, l16 = lane & 15;

  // staging mapping: thread t -> panel chunk t (row = sb2*64 + r, col kq)
  const int u = tid & 255;
  const int sb2 = tid >> 8;                     // 0..1
  const int r = u >> 2;                         // row within 64-row segment
  const int es = (r ^ (r >> 2)) & 3;
  const int kq = (u & 3) ^ es;                  // permuted k-quarter

  const h16* pa[2][NA];
  const h16* pb[2][NB];
#pragma unroll
  for (int s = 0; s < NA; s++) {
    const long row = tileM + sb2 * 64 + r + 128 * s;
    pa[0][s] = sa.p0 + (size_t)b * sa.bstr0 + row * (long)sa.s0 + kq * 8;
    pa[1][s] = sa.p1 + (size_t)b * sa.bstr1 + row * (long)sa.s1 + kq * 8 - sa.ksplit;
  }
#pragma unroll
  for (int s = 0; s < NB; s++) {
    const long row = tileN + sb2 * 64 + r + 128 * s;
    pb[0][s] = sb.p0 + (size_t)b * sb.bstr0 + row * (long)sb.s0 + kq * 8;
    pb[1][s] = sb.p1 + (size_t)b * sb.bstr1 + row * (long)sb.s1 + kq * 8 - sb.ksplit;
  }

  // fragment LDS element offsets (buf 0); e depends only on l16
  const int ef = (l16 ^ (l16 >> 2)) & 3;
  int offA[WM], offB[WN];
#pragma unroll
  for (int i = 0; i < WM; i++) {
    const int row = wr * (WM * 16) + i * 16 + l16;
    offA[i] = (row * 4 + (quad ^ ef)) * 8;
  }
#pragma unroll
  for (int j = 0; j < WN; j++) {
    const int row = wc * (WN * 16) + j * 16 + l16;
    offB[j] = AE + (row * 4 + (quad ^ ef)) * 8;
  }

  f32x4 acc[WM][WN] = {};
  const int T = K >> 5;

  auto dmaA = [&](int t, int off) {
    const int k0 = t * 32;
    h16* base = lds + off + tid * 8;
    const int sel = (k0 >= sa.ksplit);
#pragma unroll
    for (int s = 0; s < NA; s++) ASYNC16(pa[sel][s] + k0, base + 4096 * s);
  };
  auto dmaB = [&](int t, int off) {
    const int k0 = t * 32;
    h16* base = lds + off + AE + tid * 8;
    const int sel = (k0 >= sb.ksplit);
#pragma unroll
    for (int s = 0; s < NB; s++) ASYNC16(pb[sel][s] + k0, base + 4096 * s);
  };

  h16x8 bf[WN];  // B frags persist phase0 -> phase1
  auto phase0 = [&](int off) {
    h16x8 af[HM];
#pragma unroll
    for (int j = 0; j < WN; j++) bf[j] = *(const h16x8*)(lds + off + offB[j]);
#pragma unroll
    for (int i = 0; i < HM; i++) af[i] = *(const h16x8*)(lds + off + offA[i]);
    __builtin_amdgcn_s_setprio(1);
#pragma unroll
    for (int i = 0; i < HM; i++)
#pragma unroll
      for (int j = 0; j < WN; j++)
        acc[i][j] = __builtin_amdgcn_mfma_f32_16x16x32_f16(af[i], bf[j], acc[i][j], 0, 0, 0);
    __builtin_amdgcn_s_setprio(0);
  };
  auto phase1 = [&](int off) {
    h16x8 af[WM - HM];
#pragma unroll
    for (int i = 0; i < WM - HM; i++) af[i] = *(const h16x8*)(lds + off + offA[HM + i]);
    __builtin_amdgcn_s_setprio(1);
#pragma unroll
    for (int i = 0; i < WM - HM; i++)
#pragma unroll
      for (int j = 0; j < WN; j++)
        acc[HM + i][j] = __builtin_amdgcn_mfma_f32_16x16x32_f16(af[i], bf[j], acc[HM + i][j], 0, 0, 0);
    __builtin_amdgcn_s_setprio(0);
  };

  // prologue: 2 tiles in flight
  dmaA(0, 0); dmaB(0, 0);
  dmaA(1, BUFE); dmaB(1, BUFE);

  int co = 0;            // buffer offset to consume (tile t)
  int no = 2 * BUFE;     // buffer offset for issue (tile t+2)
  for (int t = 0; t < T - 1; ++t) {
    // own dma(t) done; dma(t+1) stays in flight (counted wait, no drain)
    if constexpr (LT == 4) asm volatile("s_waitcnt vmcnt(4)" ::: "memory");
    else                   asm volatile("s_waitcnt vmcnt(2)" ::: "memory");
    __builtin_amdgcn_s_barrier();            // all waves' dma(t) done; WAR gate
    asm volatile("" ::: "memory");
    __builtin_amdgcn_sched_barrier(0);
    if (t + 2 < T) dmaA(t + 2, no);
    phase0(co);
    __builtin_amdgcn_s_barrier();            // stagger waves across pipes
    asm volatile("" ::: "memory");
    __builtin_amdgcn_sched_barrier(0);
    if (t + 2 < T) dmaB(t + 2, no);
    phase1(co);
    co = (co == 2 * BUFE) ? 0 : co + BUFE;
    no = (no == 2 * BUFE) ? 0 : no + BUFE;
  }
  // last K-step: nothing younger in flight -> full drain
  asm volatile("s_waitcnt vmcnt(0)" ::: "memory");
  __builtin_amdgcn_s_barrier();
  asm volatile("" ::: "memory");
  __builtin_amdgcn_sched_barrier(0);
  phase0(co);
  __builtin_amdgcn_s_barrier();
  asm volatile("" ::: "memory");
  __builtin_amdgcn_sched_barrier(0);
  phase1(co);

#pragma unroll
  for (int i = 0; i < WM; i++) {
#pragma unroll
    for (int j = 0; j < WN; j++) {
      const int gm0 = (int)tileM + wr * (WM * 16) + i * 16 + quad * 4;
      const int gn  = (int)tileN + wc * (WN * 16) + j * 16 + l16;
#pragma unroll
      for (int rr = 0; rr < 4; rr++) epi(b, gm0 + rr, gn, acc[i][j][rr]);
    }
  }
}

// --- epilogues --------------------------------------------------------------
// Dense GEMM: A = [W_x|W_y] (1024 rows), Bt = node (all batches), C[o][node].
struct EpiDense {
  const float* w;   // gate per node (indexed by gn)
  h16* stackA;      // gm <  512 -> stackA[b][gm][offA + l]
  h16* stackB;      // gm >= 512 -> stackB[b][gm-512][offB + l]
  int lnShift;      // nodes-per-batch shift: 9 (d) or 7 (q)
  int offA, offB;
  __device__ void operator()(int, int gm, int gn, float v) const {
    const int b = gn >> lnShift, l = gn & ((1 << lnShift) - 1);
    const h16 sv = (h16)(w[gn] * v);
    if (gm < 512)
      stackA[((size_t)b * 512 + gm) * 640 + offA + l] = sv;
    else
      stackB[((size_t)b * 512 + (gm - 512)) * 640 + offB + l] = sv;
  }
};
// Agg GEMM: A = [mask'|node], Bt = [stackT|W_self], C[i][c] = self + msg/nb.
// nodeNext == nullptr on the last iteration (result never re-read).
struct EpiAgg {
  const float* bias;  // b_self[c]
  float* out;         // fp32 final output or nullptr
  h16* nodeNext;      // next-iteration node buffer [i][c], or nullptr
  int rowsPerB;       // 512 (d) or 128 (q)
  __device__ void operator()(int b, int gm, int gn, float v) const {
    const size_t row = (size_t)b * rowsPerB + gm;
    const float val = fmaxf(v + bias[gn], 0.f);
    if (out) out[row * 512 + gn] = val;
    if (nodeNext) nodeNext[row * 512 + gn] = (h16)val;
  }
};

// ---------------------------------------------------------------------------
// Combined dense launch: 640 blocks of 512 thr. g = x*160 + yy; x = M-tile of
// 256 (0..3), yy<128 -> d-job (tileN=yy*256), else q-job (yy-128). Same-yy
// blocks are 160 apart => same XCD (L2 reuse of the shared node B-panel).
// ---------------------------------------------------------------------------
__global__ __launch_bounds__(512, 2) void k_dense(Src saD, Src sbD, EpiDense epiD,
                                                  Src saQ, Src sbQ, EpiDense epiQ) {
  __shared__ __align__(16) h16 lds[3 * (256 * 32 + 256 * 32)];  // 96 KB, 3 bufs
  const int g = blockIdx.x;
  const int x = g / 160;
  const int yy = g % 160;
  if (yy < 128)
    gemm_body<8, 4>(0, (long)x * 256, (long)yy * 256, saD, sbD, 512, epiD, lds);
  else
    gemm_body<8, 4>(0, (long)x * 256, (long)(yy - 128) * 256, saQ, sbQ, 512, epiQ, lds);
}

// Combined agg launch: 512 blocks of 512 thr. g = unit*64 + b.
// unit<4: d-job 256x256 (x=unit>>1, y=unit&1) -> 256 blocks = dispatch round 1
// (all CUs). unit>=4: q-job 128x128 (tileN=(unit-4)*128) -> 256 blocks =
// round 2 (all CUs) -> no tail. Same-batch blocks 64 apart => same XCD.
__global__ __launch_bounds__(512, 2) void k_agg(Src saD, Src sbD, EpiAgg epiD,
                                                Src saQ, Src sbQ, EpiAgg epiQ) {
  __shared__ __align__(16) h16 lds[3 * (256 * 32 + 256 * 32)];  // 96 KB, 3 bufs
  const int g = blockIdx.x;
  const int b = g & 63;
  const int unit = g >> 6;
  if (unit < 4)
    gemm_body<8, 4>(b, (long)(unit >> 1) * 256, (long)(unit & 1) * 256, saD, sbD, KAGG, epiD, lds);
  else
    gemm_body<4, 2>(b, 0L, (long)(unit - 4) * 128, saQ, sbQ, KAGG, epiQ, lds);
}

// --- small kernels ----------------------------------------------------------
__global__ __launch_bounds__(256) void k_convert(const float* __restrict__ dn,
                                                 const float* __restrict__ qn,
                                                 h16* __restrict__ dnb,
                                                 h16* __restrict__ qnb) {
  const size_t i4 = ((size_t)blockIdx.x * 256 + threadIdx.x) * 4;
  constexpr size_t TD = (size_t)MD * DIM;
  const float* src; h16* dst; size_t idx;
  if (i4 < TD) { src = dn; dst = dnb; idx = i4; }
  else         { src = qn; dst = qnb; idx = i4 - TD; }
  const float4 v = *(const float4*)&src[idx];
  h16x4 o; o.x = (h16)v.x; o.y = (h16)v.y; o.z = (h16)v.z; o.w = (h16)v.w;
  *(h16x4*)&dst[idx] = o;
}

__global__ __launch_bounds__(256) void k_wcat(const float* __restrict__ Wself,
                                              const float* __restrict__ Wdd,
                                              const float* __restrict__ Wqd,
                                              const float* __restrict__ Wqq,
                                              const float* __restrict__ Wdq,
                                              h16* __restrict__ catD,
                                              h16* __restrict__ catQ) {
  const int i = blockIdx.x * 256 + threadIdx.x;  // < 1536*512
  float vD, vQ;
  if (i < 512 * 512)       { vD = Wself[i];            vQ = vD; }
  else if (i < 1024 * 512) { vD = Wdd[i - 512 * 512];  vQ = Wqq[i - 512 * 512]; }
  else                     { vD = Wqd[i - 1024 * 512]; vQ = Wdq[i - 1024 * 512]; }
  catD[i] = (h16)vD; catQ[i] = (h16)vQ;
}

// maskD'[b][i][j] = graph/nb : j<512 dd, else dq (premultiplied by 1/max(nb,1))
__global__ __launch_bounds__(256) void k_maskD(const int* __restrict__ dd,
                                               const int* __restrict__ dq,
                                               h16* __restrict__ maskD) {
  const int row = blockIdx.x * 4 + (threadIdx.x >> 6);
  const int lane = threadIdx.x & 63;
  const int* pdd = dd + (size_t)row * 512;
  const int* pdq = dq + (size_t)row * 128;
  h16* pm = maskD + (size_t)row * 640;
  float vals[10];
  float s = 0.f;
#pragma unroll
  for (int t = 0; t < 10; t++) {
    const int j = lane + t * 64;
    const float v = (float)((j < 512) ? pdd[j] : pdq[j - 512]);
    vals[t] = v; s += v;
  }
  for (int m = 32; m; m >>= 1) s += __shfl_xor(s, m);
  const float inv = 1.f / fmaxf(s, 1.f);
#pragma unroll
  for (int t = 0; t < 10; t++) pm[lane + t * 64] = (h16)(vals[t] * inv);
}

__global__ __launch_bounds__(256) void k_maskQ(const int* __restrict__ qq,
                                               const int* __restrict__ qd,
                                               h16* __restrict__ maskQ) {
  const int row = blockIdx.x * 4 + (threadIdx.x >> 6);
  const int lane = threadIdx.x & 63;
  const int* pqq = qq + (size_t)row * 128;
  const int* pqd = qd + (size_t)row * 512;
  h16* pm = maskQ + (size_t)row * 640;
  float vals[10];
  float s = 0.f;
#pragma unroll
  for (int t = 0; t < 10; t++) {
    const int j = lane + t * 64;
    const float v = (float)((j < 128) ? pqq[j] : pqd[j - 128]);
    vals[t] = v; s += v;
  }
  for (int m = 32; m; m >>= 1) s += __shfl_xor(s, m);
  const float inv = 1.f / fmaxf(s, 1.f);
#pragma unroll
  for (int t = 0; t < 10; t++) pm[lane + t * 64] = (h16)(vals[t] * inv);
}

// sigmoid gate per node row: one wave per row (d rows then q rows)
__global__ __launch_bounds__(256) void k_w(const h16* __restrict__ dnb,
                                           const h16* __restrict__ qnb,
                                           const float* __restrict__ Wnw,
                                           const float* __restrict__ bnw,
                                           float* __restrict__ d_w,
                                           float* __restrict__ q_w,
                                           float* __restrict__ adw,
                                           float* __restrict__ aqw, int it) {
  const int row = blockIdx.x * 4 + (threadIdx.x >> 6);
  const int lane = threadIdx.x & 63;
  const bool isD = row < MD;
  const h16* node = isD ? dnb + (size_t)row * 512 : qnb + (size_t)(row - MD) * 512;
  const h16x8 v = *(const h16x8*)&node[lane * 8];
  const float4 w0 = *(const float4*)&Wnw[lane * 8];
  const float4 w1 = *(const float4*)&Wnw[lane * 8 + 4];
  float s = (float)v[0] * w0.x + (float)v[1] * w0.y + (float)v[2] * w0.z +
            (float)v[3] * w0.w + (float)v[4] * w1.x + (float)v[5] * w1.y +
            (float)v[6] * w1.z + (float)v[7] * w1.w;
  for (int m = 32; m; m >>= 1) s += __shfl_xor(s, m);
  if (lane == 0) {
    const float w = 1.f / (1.f + expf(-(s + bnw[0])));
    if (isD) {
      d_w[row] = w;
      adw[((size_t)(row >> 9) * STEPS + it) * 512 + (row & 511)] = w;
    } else {
      const int rq = row - MD;
      q_w[rq] = w;
      aqw[((size_t)(rq >> 7) * STEPS + it) * 128 + (rq & 127)] = w;
    }
  }
}

// ---------------------------------------------------------------------------
extern "C" void kernel_launch(void* const* d_in, const int* in_sizes, int n_in,
                              void* d_out, int out_size, void* d_ws, size_t ws_size,
                              hipStream_t stream) {
  (void)in_sizes; (void)n_in; (void)out_size; (void)ws_size;

  const float* d_node = (const float*)d_in[0];
  const float* q_node = (const float*)d_in[1];
  const int*   qq     = (const int*)d_in[2];
  const int*   dq     = (const int*)d_in[3];
  const int*   dd     = (const int*)d_in[4];
  const int*   qd     = (const int*)d_in[5];
  const float* W_nw   = (const float*)d_in[6];
  const float* b_nw   = (const float*)d_in[7];
  const float* W_self = (const float*)d_in[8];
  const float* b_self = (const float*)d_in[9];
  const float* W_dd   = (const float*)d_in[10];
  const float* W_qq   = (const float*)d_in[11];
  const float* W_dq   = (const float*)d_in[12];
  const float* W_qd   = (const float*)d_in[13];

  float* outd = (float*)d_out;                  // [B,Ld,D]
  float* outq = outd + (size_t)MD * DIM;        // [B,Lq,D]
  float* adw  = outq + (size_t)MQ * DIM;        // [B,STEPS,Ld]
  float* aqw  = adw + (size_t)B_ * STEPS * LD;  // [B,STEPS,Lq]

  char* p = (char*)d_ws;
  auto alloc = [&](size_t bytes) { char* r = p; p += (bytes + 255) & ~(size_t)255; return r; };
  h16* dnode[2], *qnode[2];
  dnode[0] = (h16*)alloc((size_t)MD * DIM * 2);
  dnode[1] = (h16*)alloc((size_t)MD * DIM * 2);
  qnode[0] = (h16*)alloc((size_t)MQ * DIM * 2);
  qnode[1] = (h16*)alloc((size_t)MQ * DIM * 2);
  h16* catD    = (h16*)alloc((size_t)1536 * 512 * 2);
  h16* catQ    = (h16*)alloc((size_t)1536 * 512 * 2);
  h16* maskD   = (h16*)alloc((size_t)B_ * LD * KST * 2);
  h16* maskQ   = (h16*)alloc((size_t)B_ * LQ * KST * 2);
  h16* stackDT = (h16*)alloc((size_t)B_ * 512 * KST * 2);
  h16* stackQT = (h16*)alloc((size_t)B_ * 512 * KST * 2);
  float* d_wb  = (float*)alloc((size_t)MD * 4);
  float* q_wb  = (float*)alloc((size_t)MQ * 4);

  // one-time prep
  k_convert<<<dim3((MD * DIM + MQ * DIM) / 4 / 256), 256, 0, stream>>>(d_node, q_node, dnode[0], qnode[0]);
  k_wcat<<<dim3(1536 * 512 / 256), 256, 0, stream>>>(W_self, W_dd, W_qd, W_qq, W_dq, catD, catQ);
  k_maskD<<<dim3(MD / 4), 256, 0, stream>>>(dd, dq, maskD);
  k_maskQ<<<dim3(MQ / 4), 256, 0, stream>>>(qq, qd, maskQ);

  for (int it = 0; it < STEPS; it++) {
    const bool last = (it == STEPS - 1);
    h16* ncur_d = dnode[it & 1];
    h16* nnext_d = dnode[(it & 1) ^ 1];
    h16* ncur_q = qnode[it & 1];
    h16* nnext_q = qnode[(it & 1) ^ 1];

    k_w<<<dim3((MD + MQ) / 4), 256, 0, stream>>>(ncur_d, ncur_q, W_nw, b_nw, d_wb, q_wb, adw, aqw, it);

    // combined dense: d-job A=catD[512:1536]=[W_dd|W_qd] Bt=dnode;
    //                 q-job A=catQ[512:1536]=[W_qq|W_dq] Bt=qnode
    {
      Src saD{catD + 512 * 512, 512, 0, catD + 512 * 512, 512, 0, 512};
      Src sbD{ncur_d, 512, 0, ncur_d, 512, 0, 512};
      Src saQ{catQ + 512 * 512, 512, 0, catQ + 512 * 512, 512, 0, 512};
      Src sbQ{ncur_q, 512, 0, ncur_q, 512, 0, 512};
      k_dense<<<dim3(640), 512, 0, stream>>>(
          saD, sbD, EpiDense{d_wb, stackDT, stackQT, 9, 0, 128},
          saQ, sbQ, EpiDense{q_wb, stackQT, stackDT, 7, 0, 512});
    }
    // combined agg: d-job A=[maskD'|dnode] Bt=[stackDT|W_self];
    //               q-job A=[maskQ'|qnode] Bt=[stackQT|W_self]
    {
      Src saD{maskD, 640, (long)LD * KST, ncur_d, 512, (long)LD * DIM, KST};
      Src sbD{stackDT, 640, (long)512 * KST, catD, 512, 0, KST};
      Src saQ{maskQ, 640, (long)LQ * KST, ncur_q, 512, (long)LQ * DIM, KST};
      Src sbQ{stackQT, 640, (long)512 * KST, catQ, 512, 0, KST};
      k_agg<<<dim3(512), 512, 0, stream>>>(
          saD, sbD, EpiAgg{b_self, last ? outd : nullptr, last ? nullptr : nnext_d, 512},
          saQ, sbQ, EpiAgg{b_self, last ? outq : nullptr, last ? nullptr : nnext_q, 128});
    }
  }
}